// Round 1
// baseline (19.105 us; speedup 1.0000x reference)
//
#include <hip/hip_runtime.h>
#include <hip/hip_bf16.h>

#define DIM 128
#define ROW 16

// One wave (64 lanes) per batch row. Each lane holds 2 consecutive floats of
// the 128-dim embedding (float2 load = 8B/lane, 512B/row, fully coalesced).
__global__ __launch_bounds__(64) void n2v_row_kernel(
    const float* __restrict__ X,
    const int* __restrict__ rw,
    const int* __restrict__ lp,
    float* __restrict__ partial,
    int batch)
{
    const int row = blockIdx.x;
    if (row >= batch) return;
    const int lane = threadIdx.x;            // 0..63
    const int l = *lp;                        // scalar-broadcast load
    const int W = l + 1;                      // 6

    const int* walk = rw + row * ROW;

    // Load all 16 node indices (same addr per lane -> scalar-cached broadcast)
    int idx[ROW];
    #pragma unroll
    for (int j = 0; j < ROW; ++j) idx[j] = walk[j];

    // Issue all 16 gathers up-front for ILP (latency hiding).
    float2 e[ROW];
    #pragma unroll
    for (int j = 0; j < ROW; ++j) {
        e[j] = *reinterpret_cast<const float2*>(
            X + (size_t)idx[j] * DIM + lane * 2);
    }

    const float2 s = e[0];                    // start embedding fragment

    // Per-lane partial dots, then 6-step butterfly reduce each (all lanes
    // end with the full dot value).
    float dots[ROW];
    #pragma unroll
    for (int j = 0; j < ROW; ++j) {
        float p = e[j].x * s.x + e[j].y * s.y;
        #pragma unroll
        for (int off = 32; off > 0; off >>= 1)
            p += __shfl_xor(p, off, 64);
        dots[j] = p;
    }

    if (lane == 0) {
        // numerator = sum dots[1..W-1]
        float numer = 0.f;
        for (int j = 1; j < W; ++j) numer += dots[j];

        // denom: first W entries masked by "not a duplicate of an earlier
        // position"; tail entries always included.
        float denom = 0.f;
        for (int j = 0; j < ROW; ++j) {
            bool keep = true;
            if (j < W) {
                for (int i = 0; i < j; ++i) {
                    if (idx[i] == idx[j]) { keep = false; break; }
                }
            }
            if (keep) denom += __expf(dots[j]) * 0.f + expf(dots[j]);
        }

        const float loss = (float)l * logf(denom) - numer;
        partial[row] = loss;
    }
}

// Deterministic single-block mean of the 4096 per-row losses.
__global__ __launch_bounds__(256) void n2v_reduce_kernel(
    const float* __restrict__ partial,
    float* __restrict__ out,
    int n)
{
    __shared__ float sm[256];
    float acc = 0.f;
    for (int i = threadIdx.x; i < n; i += 256) acc += partial[i];
    sm[threadIdx.x] = acc;
    __syncthreads();
    for (int s = 128; s > 0; s >>= 1) {
        if (threadIdx.x < (unsigned)s) sm[threadIdx.x] += sm[threadIdx.x + s];
        __syncthreads();
    }
    if (threadIdx.x == 0) out[0] = sm[0] / (float)n;
}

extern "C" void kernel_launch(void* const* d_in, const int* in_sizes, int n_in,
                              void* d_out, int out_size, void* d_ws, size_t ws_size,
                              hipStream_t stream)
{
    const float* X  = (const float*)d_in[0];
    const int*   rw = (const int*)d_in[1];
    const int*   lp = (const int*)d_in[2];
    float* out = (float*)d_out;

    const int batch = in_sizes[1] / ROW;      // 4096
    float* partial = (float*)d_ws;            // batch floats of scratch

    n2v_row_kernel<<<batch, 64, 0, stream>>>(X, rw, lp, partial, batch);
    n2v_reduce_kernel<<<1, 256, 0, stream>>>(partial, out, batch);
}

// Round 2
// 13.107 us; speedup vs baseline: 1.4576x; 1.4576x over previous
//
#include <hip/hip_runtime.h>
#include <hip/hip_bf16.h>

#define DIM 128
#define ROW 16
#define ROWS_PER_BLOCK 16   // 256 threads: 4 waves x 4 rows/wave, 16 lanes/row

// 16 lanes per batch row. Lane g (0..15) holds floats [g*4, g*4+4) and
// [64+g*4, 64+g*4+4) of each gathered 128-dim embedding (2x float4 = 32B/lane,
// 512B/row, coalesced 256B segments per instruction).
__global__ __launch_bounds__(256) void n2v_row_kernel(
    const float* __restrict__ X,
    const int* __restrict__ rw,
    const int* __restrict__ lp,
    float* __restrict__ partial,
    int batch)
{
    const int tid  = threadIdx.x;            // 0..255
    const int g    = tid & 15;               // lane-in-group
    int row        = blockIdx.x * ROWS_PER_BLOCK + (tid >> 4);
    const bool valid = (row < batch);
    if (!valid) row = batch - 1;             // clamp: duplicate work, ignored later

    const int l = *lp;
    const int W = l + 1;                     // 6

    const int* walk = rw + row * ROW;

    // Walk indices: same address across the 16-lane group -> cache-broadcast.
    int idx[ROW];
    #pragma unroll
    for (int j = 0; j < ROW; ++j) idx[j] = walk[j];

    // Gather: all 32 float4 loads issued in an unrolled block for MLP.
    float4 a[ROW], b[ROW];
    #pragma unroll
    for (int j = 0; j < ROW; ++j) {
        const float* base = X + (size_t)idx[j] * DIM;
        a[j] = *reinterpret_cast<const float4*>(base + g * 4);
        b[j] = *reinterpret_cast<const float4*>(base + 64 + g * 4);
    }

    const float4 s0 = a[0], s1 = b[0];       // start-embedding fragment

    // Per-lane partial dots for all 16 walk steps.
    float p[ROW];
    #pragma unroll
    for (int j = 0; j < ROW; ++j) {
        p[j] = a[j].x * s0.x + a[j].y * s0.y + a[j].z * s0.z + a[j].w * s0.w
             + b[j].x * s1.x + b[j].y * s1.y + b[j].z * s1.z + b[j].w * s1.w;
    }

    // Value-halving butterfly over the 4 group bits: 16 values -> 1 in
    // 8+4+2+1 = 15 shuffles. Lane ends with full dot[brev4(g)].
    {
        // stage 0: d=1, 16 -> 8
        {
            const bool sel = (g >> 0) & 1;
            float np[8];
            #pragma unroll
            for (int i = 0; i < 8; ++i) {
                float send = sel ? p[i] : p[i + 8];
                float recv = __shfl_xor(send, 1, 64);
                np[i] = (sel ? p[i + 8] : p[i]) + recv;
            }
            #pragma unroll
            for (int i = 0; i < 8; ++i) p[i] = np[i];
        }
        // stage 1: d=2, 8 -> 4
        {
            const bool sel = (g >> 1) & 1;
            float np[4];
            #pragma unroll
            for (int i = 0; i < 4; ++i) {
                float send = sel ? p[i] : p[i + 4];
                float recv = __shfl_xor(send, 2, 64);
                np[i] = (sel ? p[i + 4] : p[i]) + recv;
            }
            #pragma unroll
            for (int i = 0; i < 4; ++i) p[i] = np[i];
        }
        // stage 2: d=4, 4 -> 2
        {
            const bool sel = (g >> 2) & 1;
            float np[2];
            #pragma unroll
            for (int i = 0; i < 2; ++i) {
                float send = sel ? p[i] : p[i + 2];
                float recv = __shfl_xor(send, 4, 64);
                np[i] = (sel ? p[i + 2] : p[i]) + recv;
            }
            p[0] = np[0]; p[1] = np[1];
        }
        // stage 3: d=8, 2 -> 1
        {
            const bool sel = (g >> 3) & 1;
            float send = sel ? p[0] : p[1];
            float recv = __shfl_xor(send, 8, 64);
            p[0] = (sel ? p[1] : p[0]) + recv;
        }
    }

    // This lane owns dot j = brev4(g).
    const int j = ((g & 1) << 3) | ((g & 2) << 1) | ((g & 4) >> 1) | ((g & 8) >> 3);
    const float dot = p[0];

    // Per-lane loss contributions (wave-parallel exp + dup mask).
    float numer_c = (j >= 1 && j < W) ? dot : 0.f;
    bool kept = true;
    if (j < W) {
        #pragma unroll
        for (int i = 0; i < ROW; ++i) {
            if (i < j && idx[i] == idx[j]) kept = false;
        }
    }
    float den_c = kept ? expf(dot) : 0.f;

    // Group reduce (bits 0..3) of the two scalars: 8 shuffles.
    #pragma unroll
    for (int d = 1; d < 16; d <<= 1) {
        numer_c += __shfl_xor(numer_c, d, 64);
        den_c   += __shfl_xor(den_c, d, 64);
    }

    // One lane per row computes the loss; block-reduce 16 rows -> 1 partial.
    __shared__ float sm[ROWS_PER_BLOCK];
    if (g == 0) {
        float loss = (float)l * logf(den_c) - numer_c;
        sm[tid >> 4] = valid ? loss : 0.f;
    }
    __syncthreads();
    if (tid == 0) {
        float acc = 0.f;
        #pragma unroll
        for (int i = 0; i < ROWS_PER_BLOCK; ++i) acc += sm[i];
        partial[blockIdx.x] = acc;
    }
}

// Single-wave deterministic reduce of the per-block partials -> mean.
__global__ __launch_bounds__(64) void n2v_reduce_kernel(
    const float* __restrict__ partial,
    float* __restrict__ out,
    int n, int batch)
{
    const int lane = threadIdx.x;
    float acc = 0.f;
    for (int i = lane; i < n; i += 64) acc += partial[i];
    #pragma unroll
    for (int d = 32; d > 0; d >>= 1) acc += __shfl_xor(acc, d, 64);
    if (lane == 0) out[0] = acc / (float)batch;
}

extern "C" void kernel_launch(void* const* d_in, const int* in_sizes, int n_in,
                              void* d_out, int out_size, void* d_ws, size_t ws_size,
                              hipStream_t stream)
{
    const float* X  = (const float*)d_in[0];
    const int*   rw = (const int*)d_in[1];
    const int*   lp = (const int*)d_in[2];
    float* out = (float*)d_out;

    const int batch = in_sizes[1] / ROW;                  // 4096
    const int grid  = (batch + ROWS_PER_BLOCK - 1) / ROWS_PER_BLOCK;  // 256
    float* partial = (float*)d_ws;

    n2v_row_kernel<<<grid, 256, 0, stream>>>(X, rw, lp, partial, batch);
    n2v_reduce_kernel<<<1, 64, 0, stream>>>(partial, out, grid, batch);
}

// Round 3
// 12.960 us; speedup vs baseline: 1.4741x; 1.0113x over previous
//
#include <hip/hip_runtime.h>
#include <hip/hip_bf16.h>

#define DIM 128
#define ROW 16
#define ROWS_PER_BLOCK 4   // 256 threads = 4 waves, one row per 64-lane wave

// One 64-lane wave per batch row. Lane holds floats [lane*2, lane*2+2) of each
// gathered 128-dim embedding (float2 = 8B/lane, 512B/row per instruction,
// fully coalesced). 16 loads in flight per wave, 16 waves/CU for TLP.
__global__ __launch_bounds__(256) void n2v_row_kernel(
    const float* __restrict__ X,
    const int* __restrict__ rw,
    const int* __restrict__ lp,
    float* __restrict__ partial,
    int batch)
{
    const int tid  = threadIdx.x;
    const int lane = tid & 63;
    const int wv   = tid >> 6;
    const int row  = blockIdx.x * ROWS_PER_BLOCK + wv;
    const bool valid = (row < batch);

    const int l = *lp;
    const int W = l + 1;                     // 6

    const int* walk = rw + (valid ? row : 0) * ROW;

    // 16 walk indices via 4 broadcast int4 loads (one 64B line).
    int idx[ROW];
    {
        int4 t0 = *reinterpret_cast<const int4*>(walk);
        int4 t1 = *reinterpret_cast<const int4*>(walk + 4);
        int4 t2 = *reinterpret_cast<const int4*>(walk + 8);
        int4 t3 = *reinterpret_cast<const int4*>(walk + 12);
        idx[0]=t0.x; idx[1]=t0.y; idx[2]=t0.z; idx[3]=t0.w;
        idx[4]=t1.x; idx[5]=t1.y; idx[6]=t1.z; idx[7]=t1.w;
        idx[8]=t2.x; idx[9]=t2.y; idx[10]=t2.z; idx[11]=t2.w;
        idx[12]=t3.x; idx[13]=t3.y; idx[14]=t3.z; idx[15]=t3.w;
    }

    // Gather: 16 float2 loads issued back-to-back (static indexing only).
    float2 e[ROW];
    #pragma unroll
    for (int j = 0; j < ROW; ++j) {
        e[j] = *reinterpret_cast<const float2*>(
            X + (size_t)idx[j] * DIM + lane * 2);
    }

    const float2 s = e[0];

    // Per-lane partial dots.
    float p[ROW];
    #pragma unroll
    for (int j = 0; j < ROW; ++j)
        p[j] = e[j].x * s.x + e[j].y * s.y;

    // Value-halving butterfly over bits 0..3 (15 shfls): each lane ends with
    // the 16-lane-group partial of dot[brev4(lane&15)].
    {
        { // 16 -> 8 (xor 1)
            const bool sel = (lane >> 0) & 1;
            float np[8];
            #pragma unroll
            for (int i = 0; i < 8; ++i) {
                float send = sel ? p[i] : p[i + 8];
                float recv = __shfl_xor(send, 1, 64);
                np[i] = (sel ? p[i + 8] : p[i]) + recv;
            }
            #pragma unroll
            for (int i = 0; i < 8; ++i) p[i] = np[i];
        }
        { // 8 -> 4 (xor 2)
            const bool sel = (lane >> 1) & 1;
            float np[4];
            #pragma unroll
            for (int i = 0; i < 4; ++i) {
                float send = sel ? p[i] : p[i + 4];
                float recv = __shfl_xor(send, 2, 64);
                np[i] = (sel ? p[i + 4] : p[i]) + recv;
            }
            #pragma unroll
            for (int i = 0; i < 4; ++i) p[i] = np[i];
        }
        { // 4 -> 2 (xor 4)
            const bool sel = (lane >> 2) & 1;
            float np[2];
            #pragma unroll
            for (int i = 0; i < 2; ++i) {
                float send = sel ? p[i] : p[i + 2];
                float recv = __shfl_xor(send, 4, 64);
                np[i] = (sel ? p[i + 2] : p[i]) + recv;
            }
            p[0] = np[0]; p[1] = np[1];
        }
        { // 2 -> 1 (xor 8)
            const bool sel = (lane >> 3) & 1;
            float send = sel ? p[0] : p[1];
            float recv = __shfl_xor(send, 8, 64);
            p[0] = (sel ? p[1] : p[0]) + recv;
        }
    }
    // Finish across the four 16-lane groups (bits 4,5).
    p[0] += __shfl_xor(p[0], 16, 64);
    p[0] += __shfl_xor(p[0], 32, 64);

    // Lane (in group 0) owns dot j = brev4(lane&15); groups 1-3 masked out.
    const int g = lane & 15;
    const int j = ((g & 1) << 3) | ((g & 2) << 1) | ((g & 4) >> 1) | ((g & 8) >> 3);
    const float dot = p[0];

    float numer_c = 0.f, den_c = 0.f;
    if ((lane >> 4) == 0) {
        numer_c = (j >= 1 && j < W) ? dot : 0.f;
        int dup = 0;
        if (j < W) {
            const int idxj = walk[j];        // L1-hit broadcast line
            #pragma unroll
            for (int i = 0; i < ROW - 1; ++i)
                dup |= (i < j) & (idx[i] == idxj);
        }
        den_c = dup ? 0.f : expf(dot);
    }

    // Wave reduce the two scalars (groups 1-3 contribute zeros).
    #pragma unroll
    for (int d = 1; d < 64; d <<= 1) {
        numer_c += __shfl_xor(numer_c, d, 64);
        den_c   += __shfl_xor(den_c, d, 64);
    }

    __shared__ float sm[ROWS_PER_BLOCK];
    if (lane == 0)
        sm[wv] = valid ? ((float)l * logf(den_c) - numer_c) : 0.f;
    __syncthreads();
    if (tid == 0)
        partial[blockIdx.x] = sm[0] + sm[1] + sm[2] + sm[3];
}

// Deterministic single-block reduce of per-block partials -> mean.
__global__ __launch_bounds__(256) void n2v_reduce_kernel(
    const float* __restrict__ partial,
    float* __restrict__ out,
    int n, int batch)
{
    float acc = 0.f;
    for (int i = threadIdx.x; i < n; i += 256) acc += partial[i];
    #pragma unroll
    for (int d = 1; d < 64; d <<= 1) acc += __shfl_xor(acc, d, 64);
    __shared__ float sm[4];
    if ((threadIdx.x & 63) == 0) sm[threadIdx.x >> 6] = acc;
    __syncthreads();
    if (threadIdx.x == 0)
        out[0] = (sm[0] + sm[1] + sm[2] + sm[3]) / (float)batch;
}

extern "C" void kernel_launch(void* const* d_in, const int* in_sizes, int n_in,
                              void* d_out, int out_size, void* d_ws, size_t ws_size,
                              hipStream_t stream)
{
    const float* X  = (const float*)d_in[0];
    const int*   rw = (const int*)d_in[1];
    const int*   lp = (const int*)d_in[2];
    float* out = (float*)d_out;

    const int batch = in_sizes[1] / ROW;                      // 4096
    const int grid  = (batch + ROWS_PER_BLOCK - 1) / ROWS_PER_BLOCK;  // 1024
    float* partial = (float*)d_ws;

    n2v_row_kernel<<<grid, 256, 0, stream>>>(X, rw, lp, partial, batch);
    n2v_reduce_kernel<<<1, 256, 0, stream>>>(partial, out, grid, batch);
}